// Round 5
// baseline (230.136 us; speedup 1.0000x reference)
//
#include <hip/hip_runtime.h>
#include <stdint.h>

#define BATCH 16384
#define SDIM 512
#define ADIM 64
#define XDIM 576      // SDIM + ADIM
#define HDIM 1024
#define NQD 64
#define QED 64

typedef __attribute__((ext_vector_type(8))) short short8;
typedef __attribute__((ext_vector_type(4))) float f32x4;

static __device__ inline unsigned short f2bf(float f) {
  unsigned int u = __float_as_uint(f);
  unsigned int r = (u + 0x7fffu + ((u >> 16) & 1u)) >> 16;
  return (unsigned short)r;
}
static __device__ inline float bf2f(unsigned short u) {
  return __uint_as_float(((unsigned int)u) << 16);
}

static __device__ inline void gload_lds16(const void* g, void* l) {
  __builtin_amdgcn_global_load_lds(
      (const __attribute__((address_space(1))) uint32_t*)g,
      (__attribute__((address_space(3))) uint32_t*)l, 16, 0, 0);
}

// LDS slot swizzle: 64B rows, 4 slots of 16B. slot ^= (r&3)^((r>>2)&3)
// gives max 2-way bank aliasing (free) for the 16-row frag reads.
static __device__ inline int sigr(int r) { return (r & 3) ^ ((r >> 2) & 3); }

// ---------------- conversion kernels ----------------

__global__ __launch_bounds__(256) void cvt_x(const float* __restrict__ st,
                                             const float* __restrict__ ac,
                                             unsigned short* __restrict__ xb) {
  const int total = BATCH * XDIM / 4;
  for (int i = blockIdx.x * blockDim.x + threadIdx.x; i < total;
       i += gridDim.x * blockDim.x) {
    const int e = i * 4;
    const int b = e / XDIM;
    const int j = e - b * XDIM;
    float4 v;
    if (j < SDIM) v = *(const float4*)(st + (size_t)b * SDIM + j);
    else          v = *(const float4*)(ac + (size_t)b * ADIM + (j - SDIM));
    ushort4 o;
    o.x = f2bf(v.x); o.y = f2bf(v.y); o.z = f2bf(v.z); o.w = f2bf(v.w);
    ((ushort4*)xb)[i] = o;
  }
}

__global__ __launch_bounds__(256) void cvt_w(const float* __restrict__ src,
                                             unsigned short* __restrict__ dst, int n4) {
  for (int i = blockIdx.x * blockDim.x + threadIdx.x; i < n4;
       i += gridDim.x * blockDim.x) {
    const float4 v = ((const float4*)src)[i];
    ushort4 o;
    o.x = f2bf(v.x); o.y = f2bf(v.y); o.z = f2bf(v.z); o.w = f2bf(v.w);
    ((ushort4*)dst)[i] = o;
  }
}

// ---------------- tau embedding head contribution (exact fp32) ----------------

__global__ void qtau_kernel(const float* __restrict__ We1, const float* __restrict__ be1,
                            const float* __restrict__ We2, const float* __restrict__ be2,
                            const float* __restrict__ Wh,  const float* __restrict__ bh,
                            float* __restrict__ qtau) {
  const int c = blockIdx.x >> 6;
  const int nq = blockIdx.x & 63;
  const int q = threadIdx.x;  // 64 threads = 1 wave
  const float tau = (float)nq / 64.0f + 0.0078125f;
  float acc = be2[c * 64 + q];
  for (int e = 0; e < 64; ++e) {
    const float t1 = fmaxf(tau * We1[c * 64 + e] + be1[c * 64 + e], 0.0f);
    acc += t1 * We2[(c * 64 + q) * 64 + e];
  }
  float v = acc * Wh[c * (HDIM + QED) + HDIM + q];
  #pragma unroll
  for (int off = 32; off; off >>= 1) v += __shfl_xor(v, off);
  if (q == 0) qtau[c * 64 + nq] = v + bh[c];
}

// ---------------- fused layer-slab kernel ----------------------------------
// Block = 64 batch rows x FULL output width (1024). 8 waves, wave w owns
// cols [w*128, w*128+128). K-loop BK=32, W-tile [1024x32] + X-tile [64x32]
// double-buffered in LDS (136 KB), streamed via global_load_lds with the
// sigr slot swizzle on both sides. After the K-loop: +bias, cross-wave
// LayerNorm (fp32), ReLU, then either bf16 store (layer 1) or fused head
// dot + qtau broadcast (layer 2, no intermediate write at all).

template <int K, bool HEAD>
__global__ __launch_bounds__(512, 2) void layer_fused(
    const unsigned short* __restrict__ A,   // [BATCH, K] bf16
    const unsigned short* __restrict__ W,   // [1024, K] bf16
    const float* __restrict__ bias,         // [1024]
    const float* __restrict__ g,            // [1024]
    const float* __restrict__ beta,         // [1024]
    unsigned short* __restrict__ Y,         // [BATCH,1024] bf16 (if !HEAD)
    const float* __restrict__ Wh,           // [1024] (if HEAD)
    const float* __restrict__ qt,           // [64]   (if HEAD)
    float* __restrict__ out)                // [BATCH,64] f32 (if HEAD)
{
  constexpr int NT = K / 32;
  __shared__ unsigned short Ws[2][1024][32];  // 128 KiB
  __shared__ unsigned short Xs[2][64][32];    // 8 KiB
  __shared__ float redS[64][8];
  __shared__ float redQ[64][8];
  __shared__ float redP[64][8];
  __shared__ float mus[64], rss[64], dotl[64], qtl[64];

  const int tid  = threadIdx.x;
  const int lane = tid & 63;
  const int wave = tid >> 6;
  const int mBase = blockIdx.x * 64;

  const int rloc = lane >> 2;                    // 0..15 (staging row in chunk)
  const int ss   = (lane & 3) ^ sigr(rloc);      // inverse-swizzled source slot

  auto stage = [&](int buf, int kt) {
    #pragma unroll
    for (int i = 0; i < 8; ++i) {
      const int rbase = wave * 128 + i * 16;
      gload_lds16(W + (size_t)(rbase + rloc) * K + kt * 32 + ss * 8,
                  &Ws[buf][rbase][0]);
    }
    if (wave < 4) {
      gload_lds16(A + (size_t)(mBase + wave * 16 + rloc) * K + kt * 32 + ss * 8,
                  &Xs[buf][wave * 16][0]);
    }
  };

  f32x4 acc[4][8];
  #pragma unroll
  for (int fm = 0; fm < 4; ++fm)
    #pragma unroll
    for (int fn = 0; fn < 8; ++fn) {
      f32x4 z = {0.f, 0.f, 0.f, 0.f};
      acc[fm][fn] = z;
    }

  short8 af[4], bw[8];

  stage(0, 0);
  __syncthreads();

  for (int t = 0; t < NT; ++t) {
    const int buf = t & 1;
    if (t + 1 < NT) stage(buf ^ 1, t + 1);
    #pragma unroll
    for (int fm = 0; fm < 4; ++fm) {
      const int r  = fm * 16 + (lane & 15);
      const int sl = (lane >> 4) ^ sigr(r);
      af[fm] = *(const short8*)&Xs[buf][r][sl * 8];
    }
    #pragma unroll
    for (int fn = 0; fn < 8; ++fn) {
      const int r  = wave * 128 + fn * 16 + (lane & 15);
      const int sl = (lane >> 4) ^ sigr(r);
      bw[fn] = *(const short8*)&Ws[buf][r][sl * 8];
    }
    __builtin_amdgcn_s_setprio(1);
    #pragma unroll
    for (int fm = 0; fm < 4; ++fm)
      #pragma unroll
      for (int fn = 0; fn < 8; ++fn)
        acc[fm][fn] = __builtin_amdgcn_mfma_f32_16x16x32_bf16(af[fm], bw[fn],
                                                              acc[fm][fn], 0, 0, 0);
    __builtin_amdgcn_s_setprio(0);
    __syncthreads();
  }

  // ---- epilogue: bias, LN stats, normalize ----
  float bcol[8], gcol[8], btc[8], whc[8];
  #pragma unroll
  for (int fn = 0; fn < 8; ++fn) {
    const int col = wave * 128 + fn * 16 + (lane & 15);
    bcol[fn] = bias[col];
    gcol[fn] = g[col];
    btc[fn]  = beta[col];
    if constexpr (HEAD) whc[fn] = Wh[col];
  }
  #pragma unroll
  for (int fm = 0; fm < 4; ++fm)
    #pragma unroll
    for (int fn = 0; fn < 8; ++fn)
      #pragma unroll
      for (int j = 0; j < 4; ++j)
        acc[fm][fn][j] += bcol[fn];

  float ps[4][4], pq[4][4];
  #pragma unroll
  for (int fm = 0; fm < 4; ++fm)
    #pragma unroll
    for (int j = 0; j < 4; ++j) {
      float s = 0.f, q = 0.f;
      #pragma unroll
      for (int fn = 0; fn < 8; ++fn) {
        const float v = acc[fm][fn][j];
        s += v; q += v * v;
      }
      ps[fm][j] = s; pq[fm][j] = q;
    }
  #pragma unroll
  for (int off = 1; off < 16; off <<= 1)
    #pragma unroll
    for (int fm = 0; fm < 4; ++fm)
      #pragma unroll
      for (int j = 0; j < 4; ++j) {
        ps[fm][j] += __shfl_xor(ps[fm][j], off);
        pq[fm][j] += __shfl_xor(pq[fm][j], off);
      }
  if ((lane & 15) == 0) {
    #pragma unroll
    for (int fm = 0; fm < 4; ++fm)
      #pragma unroll
      for (int j = 0; j < 4; ++j) {
        const int row = fm * 16 + (lane >> 4) * 4 + j;
        redS[row][wave] = ps[fm][j];
        redQ[row][wave] = pq[fm][j];
      }
  }
  __syncthreads();
  if (tid < 64) {
    float s = 0.f, q = 0.f;
    #pragma unroll
    for (int w = 0; w < 8; ++w) { s += redS[tid][w]; q += redQ[tid][w]; }
    const float mu = s * (1.0f / 1024.0f);
    const float var = q * (1.0f / 1024.0f) - mu * mu;
    mus[tid] = mu;
    rss[tid] = rsqrtf(var + 1e-5f);
    if constexpr (HEAD) qtl[tid] = qt[tid];
  }
  __syncthreads();

  float pp[4][4];
  #pragma unroll
  for (int fm = 0; fm < 4; ++fm)
    #pragma unroll
    for (int j = 0; j < 4; ++j) {
      const int row = fm * 16 + (lane >> 4) * 4 + j;
      const float mu = mus[row];
      const float rs = rss[row];
      float dp = 0.f;
      #pragma unroll
      for (int fn = 0; fn < 8; ++fn) {
        const float y = fmaxf((acc[fm][fn][j] - mu) * rs * gcol[fn] + btc[fn], 0.0f);
        if constexpr (HEAD) {
          dp += y * whc[fn];
        } else {
          Y[(size_t)(mBase + row) * HDIM + wave * 128 + fn * 16 + (lane & 15)] = f2bf(y);
        }
      }
      pp[fm][j] = dp;
    }

  if constexpr (HEAD) {
    #pragma unroll
    for (int off = 1; off < 16; off <<= 1)
      #pragma unroll
      for (int fm = 0; fm < 4; ++fm)
        #pragma unroll
        for (int j = 0; j < 4; ++j)
          pp[fm][j] += __shfl_xor(pp[fm][j], off);
    if ((lane & 15) == 0) {
      #pragma unroll
      for (int fm = 0; fm < 4; ++fm)
        #pragma unroll
        for (int j = 0; j < 4; ++j)
          redP[fm * 16 + (lane >> 4) * 4 + j][wave] = pp[fm][j];
    }
    __syncthreads();
    if (tid < 64) {
      float d = 0.f;
      #pragma unroll
      for (int w = 0; w < 8; ++w) d += redP[tid][w];
      dotl[tid] = d;
    }
    __syncthreads();
    {
      const int row = tid >> 3;
      const int n0 = (tid & 7) * 8;
      const float d = dotl[row];
      float4 o0, o1;
      o0.x = d + qtl[n0 + 0]; o0.y = d + qtl[n0 + 1];
      o0.z = d + qtl[n0 + 2]; o0.w = d + qtl[n0 + 3];
      o1.x = d + qtl[n0 + 4]; o1.y = d + qtl[n0 + 5];
      o1.z = d + qtl[n0 + 6]; o1.w = d + qtl[n0 + 7];
      float* op = out + (size_t)(mBase + row) * NQD + n0;
      *(float4*)op = o0;
      *(float4*)(op + 4) = o1;
    }
  }
}

// ---------------- launch ----------------

extern "C" void kernel_launch(void* const* d_in, const int* in_sizes, int n_in,
                              void* d_out, int out_size, void* d_ws, size_t ws_size,
                              hipStream_t stream) {
  (void)in_sizes; (void)n_in; (void)out_size; (void)ws_size;
  const float* state  = (const float*)d_in[0];
  const float* action = (const float*)d_in[1];
  const float* We1 = (const float*)d_in[2];
  const float* be1 = (const float*)d_in[3];
  const float* We2 = (const float*)d_in[4];
  const float* be2 = (const float*)d_in[5];
  const float* Wf1 = (const float*)d_in[6];
  const float* bW1 = (const float*)d_in[7];
  const float* g1  = (const float*)d_in[8];
  const float* bt1 = (const float*)d_in[9];
  const float* Wf2 = (const float*)d_in[10];
  const float* bW2 = (const float*)d_in[11];
  const float* g2  = (const float*)d_in[12];
  const float* bt2 = (const float*)d_in[13];
  const float* Wh  = (const float*)d_in[14];
  const float* bh  = (const float*)d_in[15];
  float* out = (float*)d_out;

  char* ws = (char*)d_ws;
  unsigned short* xb   = (unsigned short*)(ws);               // BATCH*576 bf16
  unsigned short* w1b  = (unsigned short*)(ws + 18874368);    // 2*1024*576 bf16
  unsigned short* w2b  = (unsigned short*)(ws + 21233664);    // 2*1024*1024 bf16
  float*          qtw  = (float*)(ws + 25427968);             // 2*64 f32
  unsigned short* ha   = (unsigned short*)(ws + 25428480);    // BATCH*1024 bf16

  cvt_x<<<2048, 256, 0, stream>>>(state, action, xb);
  cvt_w<<<1024, 256, 0, stream>>>(Wf1, w1b, 2 * HDIM * XDIM / 4);
  cvt_w<<<1024, 256, 0, stream>>>(Wf2, w2b, 2 * HDIM * HDIM / 4);
  qtau_kernel<<<128, 64, 0, stream>>>(We1, be1, We2, be2, Wh, bh, qtw);

  for (int c = 0; c < 2; ++c) {
    layer_fused<XDIM, false><<<256, 512, 0, stream>>>(
        xb, w1b + (size_t)c * HDIM * XDIM, bW1 + c * HDIM,
        g1 + c * HDIM, bt1 + c * HDIM, ha, nullptr, nullptr, nullptr);
    layer_fused<HDIM, true><<<256, 512, 0, stream>>>(
        ha, w2b + (size_t)c * HDIM * HDIM, bW2 + c * HDIM,
        g2 + c * HDIM, bt2 + c * HDIM, nullptr,
        Wh + (size_t)c * (HDIM + QED), qtw + c * 64, out + (size_t)c * BATCH * NQD);
  }
}

// Round 6
// 224.429 us; speedup vs baseline: 1.0254x; 1.0254x over previous
//
#include <hip/hip_runtime.h>
#include <stdint.h>

#define BATCH 16384
#define SDIM 512
#define ADIM 64
#define XDIM 576      // SDIM + ADIM
#define HDIM 1024
#define NQD 64
#define QED 64

typedef __attribute__((ext_vector_type(8))) short short8;
typedef __attribute__((ext_vector_type(4))) float f32x4;

static __device__ inline unsigned short f2bf(float f) {
  unsigned int u = __float_as_uint(f);
  unsigned int r = (u + 0x7fffu + ((u >> 16) & 1u)) >> 16;
  return (unsigned short)r;
}
static __device__ inline float bf2f(unsigned short u) {
  return __uint_as_float(((unsigned int)u) << 16);
}

static __device__ inline void gload_lds16(const void* g, void* l) {
  __builtin_amdgcn_global_load_lds(
      (const __attribute__((address_space(1))) uint32_t*)g,
      (__attribute__((address_space(3))) uint32_t*)l, 16, 0, 0);
}

// ---------------- conversion kernels ----------------

__global__ __launch_bounds__(256) void cvt_x(const float* __restrict__ st,
                                             const float* __restrict__ ac,
                                             unsigned short* __restrict__ xb) {
  const int total = BATCH * XDIM / 4;
  for (int i = blockIdx.x * blockDim.x + threadIdx.x; i < total;
       i += gridDim.x * blockDim.x) {
    const int e = i * 4;
    const int b = e / XDIM;
    const int j = e - b * XDIM;
    float4 v;
    if (j < SDIM) v = *(const float4*)(st + (size_t)b * SDIM + j);
    else          v = *(const float4*)(ac + (size_t)b * ADIM + (j - SDIM));
    ushort4 o;
    o.x = f2bf(v.x); o.y = f2bf(v.y); o.z = f2bf(v.z); o.w = f2bf(v.w);
    ((ushort4*)xb)[i] = o;
  }
}

// both weight matrices in one launch
__global__ __launch_bounds__(256) void cvt_w2(const float* __restrict__ s1,
                                              unsigned short* __restrict__ d1, int n1,
                                              const float* __restrict__ s2,
                                              unsigned short* __restrict__ d2, int n2) {
  for (int i = blockIdx.x * blockDim.x + threadIdx.x; i < n1 + n2;
       i += gridDim.x * blockDim.x) {
    const float4 v = (i < n1) ? ((const float4*)s1)[i] : ((const float4*)s2)[i - n1];
    ushort4 o;
    o.x = f2bf(v.x); o.y = f2bf(v.y); o.z = f2bf(v.z); o.w = f2bf(v.w);
    if (i < n1) ((ushort4*)d1)[i] = o; else ((ushort4*)d2)[i - n1] = o;
  }
}

// ---------------- tau embedding head contribution (exact fp32) ----------------

__global__ void qtau_kernel(const float* __restrict__ We1, const float* __restrict__ be1,
                            const float* __restrict__ We2, const float* __restrict__ be2,
                            const float* __restrict__ Wh,  const float* __restrict__ bh,
                            float* __restrict__ qtau) {
  const int c = blockIdx.x >> 6;
  const int nq = blockIdx.x & 63;
  const int q = threadIdx.x;  // 64 threads = 1 wave
  const float tau = (float)nq / 64.0f + 0.0078125f;
  float acc = be2[c * 64 + q];
  for (int e = 0; e < 64; ++e) {
    const float t1 = fmaxf(tau * We1[c * 64 + e] + be1[c * 64 + e], 0.0f);
    acc += t1 * We2[(c * 64 + q) * 64 + e];
  }
  float v = acc * Wh[c * (HDIM + QED) + HDIM + q];
  #pragma unroll
  for (int off = 32; off; off >>= 1) v += __shfl_xor(v, off);
  if (q == 0) qtau[c * 64 + nq] = v + bh[c];
}

// ---------------- bf16 GEMM: m97-faithful 128x128, XCD-aware grid ----------
// C[M,1024] = A[M,K] * W[1024,K]^T + bias. 4 waves (2x2), BK=32, 32 KiB LDS
// double-buffered via global_load_lds (linear layout, m97-proven), 3 blocks/CU
// for implicit wave-level pipeline overlap. Grid 1024 = 128 M-panels x 8 N;
// XCD-bijective swizzle keeps all 8 N-blocks of an A-panel on ONE XCD.

template <int K>
__global__ __launch_bounds__(256, 3) void gemm128(const unsigned short* __restrict__ A,
                                                  const unsigned short* __restrict__ W,
                                                  const float* __restrict__ bias,
                                                  unsigned short* __restrict__ C) {
  constexpr int BK = 32;
  constexpr int NT = K / BK;
  __shared__ unsigned short As[2][128 * BK];
  __shared__ unsigned short Ws[2][128 * BK];

  const int tid  = threadIdx.x;
  const int lane = tid & 63;
  const int wave = tid >> 6;
  const int wm = wave >> 1;  // 0..1
  const int wn = wave & 1;   // 0..1

  // XCD-bijective swizzle: 1024 blocks, 8 XCDs -> 128 contiguous logical each.
  // logical n-fastest: consecutive logical blocks share the A-panel.
  const int bid = (int)blockIdx.x;
  const int logical = (bid & 7) * 128 + (bid >> 3);
  const int mBase = (logical >> 3) * 128;
  const int nBase = (logical & 7) * 128;

  const int srow  = tid >> 2;  // 0..63 (4 x 16B slots per 64B row)
  const int sslot = tid & 3;

  f32x4 acc[4][4];
  #pragma unroll
  for (int m = 0; m < 4; ++m)
    #pragma unroll
    for (int n = 0; n < 4; ++n) {
      f32x4 z = {0.f, 0.f, 0.f, 0.f};
      acc[m][n] = z;
    }

  auto stage = [&](int b, int kt) {
    const unsigned short* Ag = A + (size_t)mBase * K + (size_t)kt * BK;
    const unsigned short* Wg = W + (size_t)nBase * K + (size_t)kt * BK;
    #pragma unroll
    for (int i = 0; i < 2; ++i) {
      const int r = i * 64 + srow;
      gload_lds16(Ag + (size_t)r * K + sslot * 8, &As[b][(i * 64 + wave * 16) * BK]);
      gload_lds16(Wg + (size_t)r * K + sslot * 8, &Ws[b][(i * 64 + wave * 16) * BK]);
    }
  };

  stage(0, 0);
  __syncthreads();

  int buf = 0;
  for (int kt = 0; kt < NT; ++kt) {
    if (kt + 1 < NT) stage(buf ^ 1, kt + 1);
    short8 af[4], bfr[4];
    #pragma unroll
    for (int m = 0; m < 4; ++m) {
      const int r = wm * 64 + m * 16 + (lane & 15);
      af[m] = *(const short8*)&As[buf][r * BK + (lane >> 4) * 8];
    }
    #pragma unroll
    for (int n = 0; n < 4; ++n) {
      const int r = wn * 64 + n * 16 + (lane & 15);
      bfr[n] = *(const short8*)&Ws[buf][r * BK + (lane >> 4) * 8];
    }
    #pragma unroll
    for (int m = 0; m < 4; ++m)
      #pragma unroll
      for (int n = 0; n < 4; ++n)
        acc[m][n] = __builtin_amdgcn_mfma_f32_16x16x32_bf16(af[m], bfr[n], acc[m][n], 0, 0, 0);
    __syncthreads();
    buf ^= 1;
  }

  // epilogue: bias add + bf16 round + store
  #pragma unroll
  for (int m = 0; m < 4; ++m) {
    const int r0 = mBase + wm * 64 + m * 16 + (lane >> 4) * 4;
    #pragma unroll
    for (int n = 0; n < 4; ++n) {
      const int col = nBase + wn * 64 + n * 16 + (lane & 15);
      const float bv = bias[col];
      #pragma unroll
      for (int j = 0; j < 4; ++j)
        C[(size_t)(r0 + j) * HDIM + col] = f2bf(acc[m][n][j] + bv);
    }
  }
}

// ---------------- row LayerNorm + ReLU (+ optional fused head) ----------------

template <bool HEAD>
__global__ __launch_bounds__(256) void ln_head(const unsigned short* __restrict__ X,
                                               const float* __restrict__ g,
                                               const float* __restrict__ bta,
                                               unsigned short* __restrict__ Y,
                                               const float* __restrict__ Wh,
                                               const float* __restrict__ qt,
                                               float* __restrict__ out) {
  const int b = blockIdx.x;
  const int tid = threadIdx.x;
  const int lane = tid & 63;
  const int wave = tid >> 6;
  __shared__ float rs_[4], rq_[4], rp_[4];

  const ushort4 xv = ((const ushort4*)(X + (size_t)b * HDIM))[tid];
  const float x0 = bf2f(xv.x), x1 = bf2f(xv.y), x2 = bf2f(xv.z), x3 = bf2f(xv.w);
  float s = x0 + x1 + x2 + x3;
  float q = x0 * x0 + x1 * x1 + x2 * x2 + x3 * x3;
  #pragma unroll
  for (int off = 32; off; off >>= 1) {
    s += __shfl_xor(s, off);
    q += __shfl_xor(q, off);
  }
  if (lane == 0) { rs_[wave] = s; rq_[wave] = q; }
  __syncthreads();
  s = rs_[0] + rs_[1] + rs_[2] + rs_[3];
  q = rq_[0] + rq_[1] + rq_[2] + rq_[3];
  const float mu = s * (1.0f / 1024.0f);
  const float var = q * (1.0f / 1024.0f) - mu * mu;
  const float rsig = rsqrtf(var + 1e-5f);

  const float4 gv = ((const float4*)g)[tid];
  const float4 bv = ((const float4*)bta)[tid];
  const float y0 = fmaxf((x0 - mu) * rsig * gv.x + bv.x, 0.0f);
  const float y1 = fmaxf((x1 - mu) * rsig * gv.y + bv.y, 0.0f);
  const float y2 = fmaxf((x2 - mu) * rsig * gv.z + bv.z, 0.0f);
  const float y3 = fmaxf((x3 - mu) * rsig * gv.w + bv.w, 0.0f);

  if constexpr (!HEAD) {
    ushort4 o;
    o.x = f2bf(y0); o.y = f2bf(y1); o.z = f2bf(y2); o.w = f2bf(y3);
    ((ushort4*)(Y + (size_t)b * HDIM))[tid] = o;
  } else {
    const float4 wv = ((const float4*)Wh)[tid];
    float p = y0 * wv.x + y1 * wv.y + y2 * wv.z + y3 * wv.w;
    #pragma unroll
    for (int off = 32; off; off >>= 1) p += __shfl_xor(p, off);
    if (lane == 0) rp_[wave] = p;
    __syncthreads();
    if (tid < 64) {
      const float qf = rp_[0] + rp_[1] + rp_[2] + rp_[3];
      out[(size_t)b * NQD + tid] = qf + qt[tid];
    }
  }
}

// ---------------- launch ----------------

extern "C" void kernel_launch(void* const* d_in, const int* in_sizes, int n_in,
                              void* d_out, int out_size, void* d_ws, size_t ws_size,
                              hipStream_t stream) {
  (void)in_sizes; (void)n_in; (void)out_size; (void)ws_size;
  const float* state  = (const float*)d_in[0];
  const float* action = (const float*)d_in[1];
  const float* We1 = (const float*)d_in[2];
  const float* be1 = (const float*)d_in[3];
  const float* We2 = (const float*)d_in[4];
  const float* be2 = (const float*)d_in[5];
  const float* Wf1 = (const float*)d_in[6];
  const float* bW1 = (const float*)d_in[7];
  const float* g1  = (const float*)d_in[8];
  const float* bt1 = (const float*)d_in[9];
  const float* Wf2 = (const float*)d_in[10];
  const float* bW2 = (const float*)d_in[11];
  const float* g2  = (const float*)d_in[12];
  const float* bt2 = (const float*)d_in[13];
  const float* Wh  = (const float*)d_in[14];
  const float* bh  = (const float*)d_in[15];
  float* out = (float*)d_out;

  char* ws = (char*)d_ws;
  unsigned short* xb   = (unsigned short*)(ws);               // BATCH*576 bf16
  unsigned short* w1b  = (unsigned short*)(ws + 18874368);    // 2*1024*576 bf16
  unsigned short* w2b  = (unsigned short*)(ws + 21233664);    // 2*1024*1024 bf16
  float*          qtw  = (float*)(ws + 25427968);             // 2*64 f32
  unsigned short* ha   = (unsigned short*)(ws + 25428480);    // BATCH*1024 bf16
  unsigned short* hb   = (unsigned short*)(ws + 58982912);    // BATCH*1024 bf16

  cvt_x<<<2048, 256, 0, stream>>>(state, action, xb);
  cvt_w2<<<2048, 256, 0, stream>>>(Wf1, w1b, 2 * HDIM * XDIM / 4,
                                   Wf2, w2b, 2 * HDIM * HDIM / 4);
  qtau_kernel<<<128, 64, 0, stream>>>(We1, be1, We2, be2, Wh, bh, qtw);

  for (int c = 0; c < 2; ++c) {
    gemm128<XDIM><<<1024, 256, 0, stream>>>(
        xb, w1b + (size_t)c * HDIM * XDIM, bW1 + c * HDIM, ha);
    ln_head<false><<<BATCH, 256, 0, stream>>>(
        ha, g1 + c * HDIM, bt1 + c * HDIM, hb, nullptr, nullptr, nullptr);
    gemm128<HDIM><<<1024, 256, 0, stream>>>(
        hb, w2b + (size_t)c * HDIM * HDIM, bW2 + c * HDIM, ha);
    ln_head<true><<<BATCH, 256, 0, stream>>>(
        ha, g2 + c * HDIM, bt2 + c * HDIM, nullptr,
        Wh + (size_t)c * (HDIM + QED), qtw + c * 64, out + (size_t)c * BATCH * NQD);
  }
}